// Round 9
// baseline (501.977 us; speedup 1.0000x reference)
//
#include <hip/hip_runtime.h>
#include <hip/hip_bf16.h>
#include <math.h>

#define N_NODES 50000
#define N_EDGES 800000
#define NFEAT   512
#define NHID    128
#define NCLASS  40
#define NPASS    4
#define ROWS_PER_PASS (N_NODES / NPASS)    // 12500
#define NCB      16                        // col buckets per row (800KB bands)
#define CB_W     (N_NODES / NCB)           // 3125
#define NCNT     (N_NODES * NCB)           // 800000 (row,bucket) counters
#define SCAN_BLOCKS ((NCNT + 1023) / 1024) // 782 (must be <= 1024 for scan_p2)
#define NSTAT    132                       // stats: [0..127] colsum, [128] sumsq
#define NB_STATS 256

typedef short bf16x8 __attribute__((ext_vector_type(8)));
typedef float f32x4  __attribute__((ext_vector_type(4)));

__device__ inline float bf2f(unsigned short u) {
    union { unsigned int i; float f; } x; x.i = ((unsigned int)u) << 16; return x.f;
}

// ---------------------------------------------------------------------------
// CSR build: (row, col-band) histogram -> 3-phase scan -> row-bucketed scatter
// ---------------------------------------------------------------------------
__global__ void hist_kernel(const int* __restrict__ rows, const int* __restrict__ cols,
                            int* __restrict__ cnt, int n) {
    int i = blockIdx.x * blockDim.x + threadIdx.x;
    if (i < n) {
        int r = rows[i];
        int cb = cols[i] / CB_W;
        atomicAdd(&cnt[r * NCB + cb], 1);
    }
}

__global__ __launch_bounds__(1024) void scan_p1_kernel(const int* __restrict__ cnt,
                                                       int* __restrict__ bsum, int n) {
    int i = blockIdx.x * 1024 + threadIdx.x;
    int v = (i < n) ? cnt[i] : 0;
    __shared__ int sm[16];
    int lane = threadIdx.x & 63, w = threadIdx.x >> 6;
    #pragma unroll
    for (int off = 32; off > 0; off >>= 1) v += __shfl_xor(v, off, 64);
    if (lane == 0) sm[w] = v;
    __syncthreads();
    if (threadIdx.x == 0) {
        int s = 0;
        #pragma unroll
        for (int j = 0; j < 16; ++j) s += sm[j];
        bsum[blockIdx.x] = s;
    }
}

// P2: 1 block, 1024 threads: bsum[0..nb) -> exclusive prefix (nb <= 1024)
__global__ __launch_bounds__(1024) void scan_p2_kernel(int* __restrict__ bsum, int nb) {
    __shared__ int wsum[16];
    int t = threadIdx.x;
    int lane = t & 63, w = t >> 6;
    int v = (t < nb) ? bsum[t] : 0;
    int x = v;
    #pragma unroll
    for (int off = 1; off < 64; off <<= 1) {
        int y = __shfl_up(x, off, 64);
        if (lane >= off) x += y;
    }
    if (lane == 63) wsum[w] = x;
    __syncthreads();
    int wbase = 0;
    for (int j = 0; j < w; ++j) wbase += wsum[j];
    if (t < nb) bsum[t] = wbase + x - v;   // exclusive
}

__global__ __launch_bounds__(1024) void scan_p3_kernel(const int* __restrict__ cnt,
                                                       const int* __restrict__ bsum,
                                                       int* __restrict__ bptr,
                                                       int* __restrict__ cursor, int n) {
    __shared__ int wsum[16];
    int b = blockIdx.x;
    int i = b * 1024 + threadIdx.x;
    int lane = threadIdx.x & 63, w = threadIdx.x >> 6;
    int v = (i < n) ? cnt[i] : 0;
    int x = v;
    #pragma unroll
    for (int off = 1; off < 64; off <<= 1) {
        int y = __shfl_up(x, off, 64);
        if (lane >= off) x += y;
    }
    if (lane == 63) wsum[w] = x;
    __syncthreads();
    int wbase = 0;
    for (int j = 0; j < w; ++j) wbase += wsum[j];
    int incl = bsum[b] + wbase + x;
    if (i < n) {
        bptr[i + 1] = incl;
        cursor[i] = incl - v;
    }
    if (i == 0) bptr[0] = 0;
}

// Row-bucketed scatter: pass p handles rows [p*12500,(p+1)*12500) -> 1.6MB dest
// region per pass stays L2-resident (R4 fix).
__global__ void scatter_kernel(const int* __restrict__ rows, const int* __restrict__ cols,
                               const float* __restrict__ vals, int* __restrict__ cursor,
                               int2* __restrict__ csr_cv, int n, int blocksPerPass) {
    int p = blockIdx.x / blocksPerPass;
    int b = blockIdx.x % blocksPerPass;
    int i = b * 256 + threadIdx.x;
    if (i >= n) return;
    int r = rows[i];
    int lo = p * ROWS_PER_PASS;
    if (r < lo || r >= lo + ROWS_PER_PASS) return;
    int c = cols[i];
    int pos = atomicAdd(&cursor[r * NCB + c / CB_W], 1);
    csr_cv[pos] = make_int2(c, __float_as_int(vals[i]));
}

// ---------------------------------------------------------------------------
// All 4 weight transposes+converts in one launch
// ---------------------------------------------------------------------------
__global__ __launch_bounds__(256) void wt_cvt_all_kernel(const float* __restrict__ W0,
        const float* __restrict__ W1, const float* __restrict__ W2,
        const float* __restrict__ Wo, __hip_bfloat16* __restrict__ Wt0,
        __hip_bfloat16* __restrict__ Wt1, __hip_bfloat16* __restrict__ Wt2,
        __hip_bfloat16* __restrict__ Wot) {
    int i = blockIdx.x * blockDim.x + threadIdx.x;
    if (i < 65536) {                                  // W0: [512,128] -> Wt0[n*512+k]
        int k = i >> 7, n = i & 127;
        Wt0[(size_t)n * 512 + k] = __float2bfloat16(W0[i]);
    } else if (i < 65536 + 16384) {
        int j = i - 65536; int k = j >> 7, n = j & 127;
        Wt1[(size_t)n * 128 + k] = __float2bfloat16(W1[j]);
    } else if (i < 65536 + 32768) {
        int j = i - 65536 - 16384; int k = j >> 7, n = j & 127;
        Wt2[(size_t)n * 128 + k] = __float2bfloat16(W2[j]);
    } else if (i < 65536 + 32768 + 8192) {            // W_out: [128,40] -> Wot[64,128] padded
        int j = i - 65536 - 32768; int k = j >> 6, n = j & 63;
        float v = (n < NCLASS) ? Wo[k * NCLASS + n] : 0.f;
        Wot[(size_t)n * 128 + k] = __float2bfloat16(v);
    }
}

// ---------------------------------------------------------------------------
// Layer-0 GEMM: A is fp32 x, converted bf16 in staging. Block 0 zeros stats_out.
// ---------------------------------------------------------------------------
template<int BM, int BN, int K>
__global__ __launch_bounds__(256) void mfma_gemm_f32a(const float* __restrict__ Xg,
                                                      const __hip_bfloat16* __restrict__ Wt,
                                                      __hip_bfloat16* __restrict__ Ob,
                                                      float* __restrict__ stats_out, int M) {
    constexpr int BK  = 64;
    constexpr int LDK = 72;
    constexpr int WN  = BN / 64;
    __shared__ short As[BM * LDK];
    __shared__ short Bs[BN * LDK];
    int t = threadIdx.x;
    if (blockIdx.x == 0 && t < NSTAT) stats_out[t] = 0.f;
    int lane = t & 63;
    int w = t >> 6;
    int wm = w / WN, wn = w % WN;
    int row0 = blockIdx.x * BM;
    int m0 = wm * 32, n0 = wn * 64;
    int l15 = lane & 15, quad = lane >> 4;

    f32x4 acc[2][4] = {};

    for (int k0 = 0; k0 < K; k0 += BK) {
        #pragma unroll
        for (int idx = t; idx < BM * 16; idx += 256) {
            int r = idx >> 4, c = idx & 15;
            float4 v = make_float4(0.f, 0.f, 0.f, 0.f);
            if (row0 + r < M)
                v = *(const float4*)(Xg + (size_t)(row0 + r) * K + k0 + c * 4);
            __hip_bfloat16 o[4] = {__float2bfloat16(v.x), __float2bfloat16(v.y),
                                   __float2bfloat16(v.z), __float2bfloat16(v.w)};
            *(short4*)(As + r * LDK + c * 4) = *(short4*)o;
        }
        #pragma unroll
        for (int idx = t; idx < BN * 8; idx += 256) {
            int r = idx >> 3, c = idx & 7;
            uint4 v = *(const uint4*)(Wt + (size_t)r * K + k0 + c * 8);
            *(uint4*)(Bs + r * LDK + c * 8) = v;
        }
        __syncthreads();
        #pragma unroll
        for (int ks = 0; ks < 2; ++ks) {
            bf16x8 af[2], bfv[4];
            #pragma unroll
            for (int mt = 0; mt < 2; ++mt)
                af[mt] = *(const bf16x8*)(As + (m0 + mt * 16 + l15) * LDK + ks * 32 + quad * 8);
            #pragma unroll
            for (int nt = 0; nt < 4; ++nt)
                bfv[nt] = *(const bf16x8*)(Bs + (n0 + nt * 16 + l15) * LDK + ks * 32 + quad * 8);
            #pragma unroll
            for (int mt = 0; mt < 2; ++mt)
                #pragma unroll
                for (int nt = 0; nt < 4; ++nt)
                    acc[mt][nt] = __builtin_amdgcn_mfma_f32_16x16x32_bf16(
                        af[mt], bfv[nt], acc[mt][nt], 0, 0, 0);
        }
        __syncthreads();
    }
    #pragma unroll
    for (int mt = 0; mt < 2; ++mt) {
        #pragma unroll
        for (int reg = 0; reg < 4; ++reg) {
            int row = row0 + m0 + mt * 16 + quad * 4 + reg;
            if (row < M) {
                #pragma unroll
                for (int nt = 0; nt < 4; ++nt)
                    Ob[(size_t)row * BN + n0 + nt * 16 + l15] =
                        __float2bfloat16(acc[mt][nt][reg]);
            }
        }
    }
}

// ---------------------------------------------------------------------------
// Fused PN+GEMM: prologue computes mu/scale from raw stats; A-staging applies
// relu((Bm-mu)*s) [+ Xb residual], optionally writes Xb. Block 0 zeros stats_out.
// ---------------------------------------------------------------------------
template<int BM, int BN, bool ADD_RESID, bool WRITE_X>
__global__ __launch_bounds__(256) void mfma_gemm_pn(const __hip_bfloat16* __restrict__ Bm,
                                                    __hip_bfloat16* __restrict__ Xb,
                                                    const float* __restrict__ stats_in,
                                                    float* __restrict__ stats_out,
                                                    const __hip_bfloat16* __restrict__ Wt,
                                                    __hip_bfloat16* __restrict__ Ob, int M) {
    constexpr int K = 128, BK = 64, LDK = 72;
    constexpr int WN = BN / 64;
    __shared__ short As[BM * LDK];
    __shared__ short Bs[BN * LDK];
    __shared__ float smu[128];
    __shared__ float sred[128];
    __shared__ float sscale;
    int t = threadIdx.x;
    if (stats_out && blockIdx.x == 0 && t < NSTAT) stats_out[t] = 0.f;
    if (t < 128) {
        float mu = stats_in[t] * (1.0f / N_NODES);
        smu[t] = mu;
        sred[t] = mu * mu;
    }
    __syncthreads();
    for (int off = 64; off > 0; off >>= 1) {
        if (t < off) sred[t] += sred[t + off];
        __syncthreads();
    }
    if (t == 0) {
        float ms = stats_in[128] * (1.0f / N_NODES) - sred[0];
        sscale = 1.0f / sqrtf(1e-6f + ms);   // PN_SCALE = 1
    }
    __syncthreads();
    float sc = sscale;

    int lane = t & 63;
    int w = t >> 6;
    int wm = w / WN, wn = w % WN;
    int row0 = blockIdx.x * BM;
    int m0 = wm * 32, n0 = wn * 64;
    int l15 = lane & 15, quad = lane >> 4;

    f32x4 acc[2][4] = {};

    for (int k0 = 0; k0 < K; k0 += BK) {
        // A stage with fused PairNorm + ReLU + residual
        #pragma unroll
        for (int idx = t; idx < BM * 8; idx += 256) {
            int r = idx >> 3, c = idx & 7;
            int gr = row0 + r;
            int k = k0 + c * 8;
            uint4 bm = make_uint4(0u, 0u, 0u, 0u);
            uint4 xo = make_uint4(0u, 0u, 0u, 0u);
            bool ok = gr < M;
            if (ok) bm = *(const uint4*)(Bm + (size_t)gr * 128 + k);
            if (ADD_RESID && ok) xo = *(const uint4*)(Xb + (size_t)gr * 128 + k);
            unsigned short* bu = (unsigned short*)&bm;
            unsigned short* xu = (unsigned short*)&xo;
            __hip_bfloat16 o[8];
            #pragma unroll
            for (int j = 0; j < 8; ++j) {
                float v = fmaxf((bf2f(bu[j]) - smu[k + j]) * sc, 0.f);
                if (ADD_RESID) v += bf2f(xu[j]);
                o[j] = __float2bfloat16(v);
            }
            *(uint4*)(As + r * LDK + c * 8) = *(uint4*)o;
            if (WRITE_X && ok) *(uint4*)(Xb + (size_t)gr * 128 + k) = *(uint4*)o;
        }
        #pragma unroll
        for (int idx = t; idx < BN * 8; idx += 256) {
            int r = idx >> 3, c = idx & 7;
            uint4 v = *(const uint4*)(Wt + (size_t)r * K + k0 + c * 8);
            *(uint4*)(Bs + r * LDK + c * 8) = v;
        }
        __syncthreads();
        #pragma unroll
        for (int ks = 0; ks < 2; ++ks) {
            bf16x8 af[2], bfv[4];
            #pragma unroll
            for (int mt = 0; mt < 2; ++mt)
                af[mt] = *(const bf16x8*)(As + (m0 + mt * 16 + l15) * LDK + ks * 32 + quad * 8);
            #pragma unroll
            for (int nt = 0; nt < 4; ++nt)
                bfv[nt] = *(const bf16x8*)(Bs + (n0 + nt * 16 + l15) * LDK + ks * 32 + quad * 8);
            #pragma unroll
            for (int mt = 0; mt < 2; ++mt)
                #pragma unroll
                for (int nt = 0; nt < 4; ++nt)
                    acc[mt][nt] = __builtin_amdgcn_mfma_f32_16x16x32_bf16(
                        af[mt], bfv[nt], acc[mt][nt], 0, 0, 0);
        }
        __syncthreads();
    }
    #pragma unroll
    for (int mt = 0; mt < 2; ++mt) {
        #pragma unroll
        for (int reg = 0; reg < 4; ++reg) {
            int row = row0 + m0 + mt * 16 + quad * 4 + reg;
            if (row < M) {
                #pragma unroll
                for (int nt = 0; nt < 4; ++nt)
                    Ob[(size_t)row * BN + n0 + nt * 16 + l15] =
                        __float2bfloat16(acc[mt][nt][reg]);
            }
        }
    }
}

// ---------------------------------------------------------------------------
// CSR SpMM, 128 feats: one wave per row (TLP supply — R7's grid-stride lost
// 18µs), half-waves take alternate edge groups. 16-edge main loop = 8 gathers
// in flight per half-wave; edge meta loads are wave-uniform -> SGPR loads.
// ---------------------------------------------------------------------------
__global__ __launch_bounds__(256) void spmm_bf16_kernel(const __hip_bfloat16* __restrict__ H,
                                                        const int* __restrict__ bptr,
                                                        const int2* __restrict__ cv,
                                                        const float* __restrict__ bias,
                                                        __hip_bfloat16* __restrict__ Bm,
                                                        int nrows) {
    int wid = (int)((blockIdx.x * blockDim.x + threadIdx.x) >> 6);
    wid = __builtin_amdgcn_readfirstlane(wid);
    int lane = threadIdx.x & 63;
    int h = lane >> 5;
    int sub = lane & 31;                   // feats [4sub .. 4sub+3]
    if (wid >= nrows) return;
    int s = bptr[wid * NCB];
    int e = bptr[wid * NCB + NCB];
    const ushort4* H4 = (const ushort4*)H; // row stride = 32 ushort4
    f32x4 acc = {0.f, 0.f, 0.f, 0.f};
    int i = s;
    for (; i + 15 < e; i += 16) {          // 16 edges/iter: half h takes i+8h..i+8h+7
        int2 cc[8];
        #pragma unroll
        for (int j = 0; j < 8; ++j) cc[j] = cv[i + 8 * h + j];
        ushort4 g[8];
        #pragma unroll
        for (int j = 0; j < 8; ++j) g[j] = H4[(size_t)cc[j].x * 32 + sub];
        #pragma unroll
        for (int j = 0; j < 8; ++j) {
            float v = __int_as_float(cc[j].y);
            acc[0] = fmaf(v, bf2f(g[j].x), acc[0]); acc[1] = fmaf(v, bf2f(g[j].y), acc[1]);
            acc[2] = fmaf(v, bf2f(g[j].z), acc[2]); acc[3] = fmaf(v, bf2f(g[j].w), acc[3]);
        }
    }
    for (; i + 7 < e; i += 8) {            // 8 edges/iter: half h takes i+4h..i+4h+3
        int2 cc[4];
        #pragma unroll
        for (int j = 0; j < 4; ++j) cc[j] = cv[i + 4 * h + j];
        ushort4 g[4];
        #pragma unroll
        for (int j = 0; j < 4; ++j) g[j] = H4[(size_t)cc[j].x * 32 + sub];
        #pragma unroll
        for (int j = 0; j < 4; ++j) {
            float v = __int_as_float(cc[j].y);
            acc[0] = fmaf(v, bf2f(g[j].x), acc[0]); acc[1] = fmaf(v, bf2f(g[j].y), acc[1]);
            acc[2] = fmaf(v, bf2f(g[j].z), acc[2]); acc[3] = fmaf(v, bf2f(g[j].w), acc[3]);
        }
    }
    for (; i + 3 < e; i += 4) {            // 4 edges: half h takes i+2h, i+2h+1
        int2 c0 = cv[i + 2 * h], c1 = cv[i + 2 * h + 1];
        ushort4 ga = H4[(size_t)c0.x * 32 + sub];
        ushort4 gb = H4[(size_t)c1.x * 32 + sub];
        float va = __int_as_float(c0.y), vb = __int_as_float(c1.y);
        acc[0] = fmaf(va, bf2f(ga.x), acc[0]); acc[1] = fmaf(va, bf2f(ga.y), acc[1]);
        acc[2] = fmaf(va, bf2f(ga.z), acc[2]); acc[3] = fmaf(va, bf2f(ga.w), acc[3]);
        acc[0] = fmaf(vb, bf2f(gb.x), acc[0]); acc[1] = fmaf(vb, bf2f(gb.y), acc[1]);
        acc[2] = fmaf(vb, bf2f(gb.z), acc[2]); acc[3] = fmaf(vb, bf2f(gb.w), acc[3]);
    }
    for (; i < e; ++i) {                   // tail: half0 only
        int2 c = cv[i];
        if (h == 0) {
            float v = __int_as_float(c.y);
            ushort4 g = H4[(size_t)c.x * 32 + sub];
            acc[0] = fmaf(v, bf2f(g.x), acc[0]); acc[1] = fmaf(v, bf2f(g.y), acc[1]);
            acc[2] = fmaf(v, bf2f(g.z), acc[2]); acc[3] = fmaf(v, bf2f(g.w), acc[3]);
        }
    }
    #pragma unroll
    for (int c = 0; c < 4; ++c) acc[c] += __shfl_xor(acc[c], 32);
    if (h == 0) {
        float4 b4 = *(const float4*)(bias + 4 * sub);
        __hip_bfloat16 o[4] = {__float2bfloat16(acc[0] + b4.x), __float2bfloat16(acc[1] + b4.y),
                               __float2bfloat16(acc[2] + b4.z), __float2bfloat16(acc[3] + b4.w)};
        *(ushort4*)(Bm + (size_t)wid * 128 + 4 * sub) = *(ushort4*)o;
    }
}

// ---------------------------------------------------------------------------
// PairNorm raw stats on bf16 Bm: colsum -> stats[0..127], sumsq -> stats[128]
// ---------------------------------------------------------------------------
__global__ __launch_bounds__(256) void stats_kernel(const __hip_bfloat16* __restrict__ B,
                                                    float* __restrict__ stats, int n2) {
    int tid = blockIdx.x * blockDim.x + threadIdx.x;
    int stride = NB_STATS * 256;
    const __hip_bfloat162* B2 = (const __hip_bfloat162*)B;
    float cs0 = 0.f, cs1 = 0.f, sq = 0.f;
    for (int j = tid; j < n2; j += stride) {
        __hip_bfloat162 h = B2[j];
        float a = __bfloat162float(h.x), b = __bfloat162float(h.y);
        cs0 += a; cs1 += b;
        sq = fmaf(a, a, sq); sq = fmaf(b, b, sq);
    }
    __shared__ float s0[256], s1[256], ss[256];
    int t = threadIdx.x;
    s0[t] = cs0; s1[t] = cs1; ss[t] = sq;
    __syncthreads();
    if (t < 64) {   // thread t owns column pair t (stride % 64 == 0)
        float a = s0[t] + s0[t + 64] + s0[t + 128] + s0[t + 192];
        float b = s1[t] + s1[t + 64] + s1[t + 128] + s1[t + 192];
        atomicAdd(&stats[2 * t], a);
        atomicAdd(&stats[2 * t + 1], b);
    }
    __syncthreads();
    for (int off = 128; off > 0; off >>= 1) {
        if (t < off) ss[t] += ss[t + off];
        __syncthreads();
    }
    if (t == 0) atomicAdd(&stats[128], ss[0]);
}

// ---------------------------------------------------------------------------
// Final SpMM, 64-wide G (cols 40..63 zero): half-wave 128B gathers, 8-edge unroll
// ---------------------------------------------------------------------------
__global__ __launch_bounds__(256) void spmm_out_kernel(const __hip_bfloat16* __restrict__ G,
                                                       const int* __restrict__ bptr,
                                                       const int2* __restrict__ cv,
                                                       const float* __restrict__ bias,
                                                       float* __restrict__ out, int nrows) {
    int wid = (int)((blockIdx.x * blockDim.x + threadIdx.x) >> 6);
    wid = __builtin_amdgcn_readfirstlane(wid);
    int lane = threadIdx.x & 63;
    int h = lane >> 5;
    int sub = lane & 31;                    // feats {2sub, 2sub+1}
    if (wid >= nrows) return;
    int s = bptr[wid * NCB];
    int e = bptr[wid * NCB + NCB];
    const __hip_bfloat162* G2 = (const __hip_bfloat162*)G;   // row stride 32
    float a0 = 0.f, a1 = 0.f;
    int i = s;
    for (; i + 15 < e; i += 16) {
        int2 cc[8];
        #pragma unroll
        for (int j = 0; j < 8; ++j) cc[j] = cv[i + 8 * h + j];
        __hip_bfloat162 g[8];
        #pragma unroll
        for (int j = 0; j < 8; ++j) g[j] = G2[(size_t)cc[j].x * 32 + sub];
        #pragma unroll
        for (int j = 0; j < 8; ++j) {
            float v = __int_as_float(cc[j].y);
            a0 = fmaf(v, __bfloat162float(g[j].x), a0);
            a1 = fmaf(v, __bfloat162float(g[j].y), a1);
        }
    }
    for (; i + 7 < e; i += 8) {
        int2 cc[4];
        #pragma unroll
        for (int j = 0; j < 4; ++j) cc[j] = cv[i + 4 * h + j];
        __hip_bfloat162 g[4];
        #pragma unroll
        for (int j = 0; j < 4; ++j) g[j] = G2[(size_t)cc[j].x * 32 + sub];
        #pragma unroll
        for (int j = 0; j < 4; ++j) {
            float v = __int_as_float(cc[j].y);
            a0 = fmaf(v, __bfloat162float(g[j].x), a0);
            a1 = fmaf(v, __bfloat162float(g[j].y), a1);
        }
    }
    for (; i + 3 < e; i += 4) {
        int2 c0 = cv[i + 2 * h], c1 = cv[i + 2 * h + 1];
        __hip_bfloat162 ga = G2[(size_t)c0.x * 32 + sub];
        __hip_bfloat162 gb = G2[(size_t)c1.x * 32 + sub];
        float va = __int_as_float(c0.y), vb = __int_as_float(c1.y);
        a0 = fmaf(va, __bfloat162float(ga.x), a0); a1 = fmaf(va, __bfloat162float(ga.y), a1);
        a0 = fmaf(vb, __bfloat162float(gb.x), a0); a1 = fmaf(vb, __bfloat162float(gb.y), a1);
    }
    for (; i < e; ++i) {
        int2 c = cv[i];
        if (h == 0) {
            float v = __int_as_float(c.y);
            __hip_bfloat162 g = G2[(size_t)c.x * 32 + sub];
            a0 = fmaf(v, __bfloat162float(g.x), a0);
            a1 = fmaf(v, __bfloat162float(g.y), a1);
        }
    }
    a0 += __shfl_xor(a0, 32);
    a1 += __shfl_xor(a1, 32);
    if (h == 0 && sub < NCLASS / 2) {
        float2 b2 = *(const float2*)(bias + 2 * sub);
        float2 o = make_float2(a0 + b2.x, a1 + b2.y);
        *(float2*)(out + (size_t)wid * NCLASS + 2 * sub) = o;
    }
}

// ---------------------------------------------------------------------------
extern "C" void kernel_launch(void* const* d_in, const int* in_sizes, int n_in,
                              void* d_out, int out_size, void* d_ws, size_t ws_size,
                              hipStream_t stream) {
    const float* x        = (const float*)d_in[0];
    const int*   edge_row = (const int*)  d_in[1];
    const int*   edge_col = (const int*)  d_in[2];
    const float* edge_val = (const float*)d_in[3];
    const float* W0 = (const float*)d_in[4];
    const float* b0 = (const float*)d_in[5];
    const float* W1 = (const float*)d_in[6];
    const float* b1 = (const float*)d_in[7];
    const float* W2 = (const float*)d_in[8];
    const float* b2 = (const float*)d_in[9];
    const float* W_out = (const float*)d_in[10];
    const float* b_out = (const float*)d_in[11];
    float* out = (float*)d_out;

    const size_t NH = (size_t)N_NODES * NHID;   // 6,400,000

    char* p = (char*)d_ws;
    __hip_bfloat16* Xb   = (__hip_bfloat16*)p;  p += NH * 2;
    __hip_bfloat16* A_bf = (__hip_bfloat16*)p;  p += NH * 2;
    __hip_bfloat16* Bm   = (__hip_bfloat16*)p;  p += NH * 2;
    __hip_bfloat16* Wt0 = (__hip_bfloat16*)p;   p += (size_t)128 * 512 * 2;
    __hip_bfloat16* Wt1 = (__hip_bfloat16*)p;   p += (size_t)128 * 128 * 2;
    __hip_bfloat16* Wt2 = (__hip_bfloat16*)p;   p += (size_t)128 * 128 * 2;
    __hip_bfloat16* Wot = (__hip_bfloat16*)p;   p += (size_t)64 * 128 * 2;
    float* statsA   = (float*)p;                p += NSTAT * 4;
    float* statsB   = (float*)p;                p += NSTAT * 4;
    int* cnt      = (int*)p;                    p += (size_t)NCNT * 4;
    int* bptr     = (int*)p;                    p += (size_t)(NCNT + 1) * 4 + 4; // int2 align
    int* cursor   = (int*)p;                    p += (size_t)NCNT * 4;
    int* bsum     = (int*)p;                    p += (size_t)SCAN_BLOCKS * 4 + 4;
    int2* csr_cv  = (int2*)p;                   p += (size_t)N_EDGES * 8;

    const int EB = (N_EDGES + 255) / 256;         // 3125 blocks per pass
    const int SPMM_GRID = (N_NODES + 3) / 4;      // 12500 (4 waves/block)

    // --- weight conversion (one launch) ---
    wt_cvt_all_kernel<<<(65536 + 32768 + 8192 + 255) / 256, 256, 0, stream>>>(
        W0, W1, W2, W_out, Wt0, Wt1, Wt2, Wot);

    // --- CSR build with col-band sub-segments (shared by all 4 SpMMs) ---
    hipMemsetAsync(cnt, 0, NCNT * sizeof(int), stream);
    hist_kernel<<<EB, 256, 0, stream>>>(edge_row, edge_col, cnt, N_EDGES);
    scan_p1_kernel<<<SCAN_BLOCKS, 1024, 0, stream>>>(cnt, bsum, NCNT);
    scan_p2_kernel<<<1, 1024, 0, stream>>>(bsum, SCAN_BLOCKS);
    scan_p3_kernel<<<SCAN_BLOCKS, 1024, 0, stream>>>(cnt, bsum, bptr, cursor, NCNT);
    scatter_kernel<<<EB * NPASS, 256, 0, stream>>>(edge_row, edge_col, edge_val, cursor,
                                                   csr_cv, N_EDGES, EB);

    // --- layer 0: GEMM (zeros statsA) -> SpMM -> stats(statsA) ---
    mfma_gemm_f32a<64, 128, 512><<<(N_NODES + 63) / 64, 256, 0, stream>>>(
        x, Wt0, A_bf, statsA, N_NODES);
    spmm_bf16_kernel<<<SPMM_GRID, 256, 0, stream>>>(A_bf, bptr, csr_cv, b0, Bm, N_NODES);
    stats_kernel<<<NB_STATS, 256, 0, stream>>>(Bm, statsA, (int)(NH / 2));

    // --- layer 1: PN(statsA)+GEMM (writes Xb=x1, zeros statsB) -> SpMM -> stats
    mfma_gemm_pn<64, 128, false, true><<<(N_NODES + 63) / 64, 256, 0, stream>>>(
        Bm, Xb, statsA, statsB, Wt1, A_bf, N_NODES);
    spmm_bf16_kernel<<<SPMM_GRID, 256, 0, stream>>>(A_bf, bptr, csr_cv, b1, Bm, N_NODES);
    stats_kernel<<<NB_STATS, 256, 0, stream>>>(Bm, statsB, (int)(NH / 2));

    // --- layer 2: PN(statsB)+resid+GEMM (Xb=x2, zeros statsA) -> SpMM -> stats
    mfma_gemm_pn<64, 128, true, true><<<(N_NODES + 63) / 64, 256, 0, stream>>>(
        Bm, Xb, statsB, statsA, Wt2, A_bf, N_NODES);
    spmm_bf16_kernel<<<SPMM_GRID, 256, 0, stream>>>(A_bf, bptr, csr_cv, b2, Bm, N_NODES);
    stats_kernel<<<NB_STATS, 256, 0, stream>>>(Bm, statsA, (int)(NH / 2));

    // --- head: PN(statsA)+resid(x2), x3 never materialized; Gp = x3 @ Wot^T ---
    mfma_gemm_pn<128, 64, true, false><<<(N_NODES + 127) / 128, 256, 0, stream>>>(
        Bm, Xb, statsA, nullptr, Wot, A_bf, N_NODES);
    spmm_out_kernel<<<(N_NODES + 3) / 4, 256, 0, stream>>>(A_bf, bptr, csr_cv, b_out,
                                                           out, N_NODES);
}

// Round 10
// 495.236 us; speedup vs baseline: 1.0136x; 1.0136x over previous
//
#include <hip/hip_runtime.h>
#include <hip/hip_bf16.h>
#include <math.h>

#define N_NODES 50000
#define N_EDGES 800000
#define NFEAT   512
#define NHID    128
#define NCLASS  40
#define NPASS    4
#define ROWS_PER_PASS (N_NODES / NPASS)    // 12500
#define NCB      8                         // col buckets per row (1.6MB bands)
#define CB_W     (N_NODES / NCB)           // 6250
#define NCNT     (N_NODES * NCB)           // 400000 (row,bucket) counters
#define SCAN_BLOCKS ((NCNT + 1023) / 1024) // 391
#define NSLICE   16                        // stats slices (contention spread)
#define SLICE_W  132                       // [0..127] colsum, [128] sumsq, pad
#define WT_BLOCKS 416                      // (65536+16384+16384+8192)/256

typedef short bf16x8 __attribute__((ext_vector_type(8)));
typedef float f32x4  __attribute__((ext_vector_type(4)));

__device__ inline float bf2f(unsigned short u) {
    union { unsigned int i; float f; } x; x.i = ((unsigned int)u) << 16; return x.f;
}

// ---------------------------------------------------------------------------
// Merged: weight transpose/convert (blocks 0..415) + edge histogram (rest)
// ---------------------------------------------------------------------------
__global__ __launch_bounds__(256) void wt_hist_kernel(const float* __restrict__ W0,
        const float* __restrict__ W1, const float* __restrict__ W2,
        const float* __restrict__ Wo, __hip_bfloat16* __restrict__ Wt0,
        __hip_bfloat16* __restrict__ Wt1, __hip_bfloat16* __restrict__ Wt2,
        __hip_bfloat16* __restrict__ Wot,
        const int* __restrict__ rows, const int* __restrict__ cols,
        int* __restrict__ cnt, int n) {
    if (blockIdx.x >= WT_BLOCKS) {
        int i = (blockIdx.x - WT_BLOCKS) * 256 + threadIdx.x;
        if (i < n) {
            int r = rows[i];
            int cb = cols[i] / CB_W;
            atomicAdd(&cnt[r * NCB + cb], 1);
        }
        return;
    }
    int i = blockIdx.x * 256 + threadIdx.x;
    if (i < 65536) {                                  // W0: [512,128] -> Wt0[n*512+k]
        int k = i >> 7, n2 = i & 127;
        Wt0[(size_t)n2 * 512 + k] = __float2bfloat16(W0[i]);
    } else if (i < 65536 + 16384) {
        int j = i - 65536; int k = j >> 7, n2 = j & 127;
        Wt1[(size_t)n2 * 128 + k] = __float2bfloat16(W1[j]);
    } else if (i < 65536 + 32768) {
        int j = i - 65536 - 16384; int k = j >> 7, n2 = j & 127;
        Wt2[(size_t)n2 * 128 + k] = __float2bfloat16(W2[j]);
    } else if (i < 65536 + 32768 + 8192) {            // W_out: [128,40] -> Wot[64,128] padded
        int j = i - 65536 - 32768; int k = j >> 6, n2 = j & 63;
        float v = (n2 < NCLASS) ? Wo[k * NCLASS + n2] : 0.f;
        Wot[(size_t)n2 * 128 + k] = __float2bfloat16(v);
    }
}

__global__ __launch_bounds__(1024) void scan_p1_kernel(const int* __restrict__ cnt,
                                                       int* __restrict__ bsum, int n) {
    int i = blockIdx.x * 1024 + threadIdx.x;
    int v = (i < n) ? cnt[i] : 0;
    __shared__ int sm[16];
    int lane = threadIdx.x & 63, w = threadIdx.x >> 6;
    #pragma unroll
    for (int off = 32; off > 0; off >>= 1) v += __shfl_xor(v, off, 64);
    if (lane == 0) sm[w] = v;
    __syncthreads();
    if (threadIdx.x == 0) {
        int s = 0;
        #pragma unroll
        for (int j = 0; j < 16; ++j) s += sm[j];
        bsum[blockIdx.x] = s;
    }
}

__global__ __launch_bounds__(512) void scan_p2_kernel(int* __restrict__ bsum, int nb) {
    __shared__ int wsum[8];
    int t = threadIdx.x;
    int lane = t & 63, w = t >> 6;
    int v = (t < nb) ? bsum[t] : 0;
    int x = v;
    #pragma unroll
    for (int off = 1; off < 64; off <<= 1) {
        int y = __shfl_up(x, off, 64);
        if (lane >= off) x += y;
    }
    if (lane == 63) wsum[w] = x;
    __syncthreads();
    int wbase = 0;
    for (int j = 0; j < w; ++j) wbase += wsum[j];
    if (t < nb) bsum[t] = wbase + x - v;   // exclusive
}

__global__ __launch_bounds__(1024) void scan_p3_kernel(const int* __restrict__ cnt,
                                                       const int* __restrict__ bsum,
                                                       int* __restrict__ bptr,
                                                       int* __restrict__ cursor, int n) {
    __shared__ int wsum[16];
    int b = blockIdx.x;
    int i = b * 1024 + threadIdx.x;
    int lane = threadIdx.x & 63, w = threadIdx.x >> 6;
    int v = (i < n) ? cnt[i] : 0;
    int x = v;
    #pragma unroll
    for (int off = 1; off < 64; off <<= 1) {
        int y = __shfl_up(x, off, 64);
        if (lane >= off) x += y;
    }
    if (lane == 63) wsum[w] = x;
    __syncthreads();
    int wbase = 0;
    for (int j = 0; j < w; ++j) wbase += wsum[j];
    int incl = bsum[b] + wbase + x;
    if (i < n) {
        bptr[i + 1] = incl;
        cursor[i] = incl - v;
    }
    if (i == 0) bptr[0] = 0;
}

// ---------------------------------------------------------------------------
// Merged: layer-0 GEMM (blocks 0..gemmBlocks-1, fp32 A converted in staging,
// block 0 zeros statsA slices) + row-bucketed scatter (remaining blocks).
// Both depend only on {wt_hist, scan_p3}; scatter rides under the GEMM.
// ---------------------------------------------------------------------------
template<int BM, int BN, int K>
__global__ __launch_bounds__(256) void gemm0_scatter_kernel(
        const float* __restrict__ Xg, const __hip_bfloat16* __restrict__ Wt,
        __hip_bfloat16* __restrict__ Ob, float* __restrict__ stats_out, int M,
        const int* __restrict__ rows, const int* __restrict__ cols,
        const float* __restrict__ vals, int* __restrict__ cursor,
        int2* __restrict__ csr_cv, int n, int blocksPerPass, int gemmBlocks) {
    constexpr int BK  = 64;
    constexpr int LDK = 72;
    constexpr int WN  = BN / 64;
    __shared__ short As[BM * LDK];
    __shared__ short Bs[BN * LDK];
    int t = threadIdx.x;

    if ((int)blockIdx.x >= gemmBlocks) {   // ---- scatter path ----
        int bb = blockIdx.x - gemmBlocks;
        int p = bb / blocksPerPass;
        int b = bb % blocksPerPass;
        int i = b * 256 + t;
        if (i >= n) return;
        int r = rows[i];
        int lo = p * ROWS_PER_PASS;
        if (r < lo || r >= lo + ROWS_PER_PASS) return;
        int c = cols[i];
        int pos = atomicAdd(&cursor[r * NCB + c / CB_W], 1);
        csr_cv[pos] = make_int2(c, __float_as_int(vals[i]));
        return;
    }

    // ---- GEMM path ----
    if (blockIdx.x == 0)
        for (int z = t; z < NSLICE * SLICE_W; z += 256) stats_out[z] = 0.f;
    int lane = t & 63;
    int w = t >> 6;
    int wm = w / WN, wn = w % WN;
    int row0 = blockIdx.x * BM;
    int m0 = wm * 32, n0 = wn * 64;
    int l15 = lane & 15, quad = lane >> 4;

    f32x4 acc[2][4] = {};

    for (int k0 = 0; k0 < K; k0 += BK) {
        #pragma unroll
        for (int idx = t; idx < BM * 16; idx += 256) {
            int r = idx >> 4, c = idx & 15;
            float4 v = make_float4(0.f, 0.f, 0.f, 0.f);
            if (row0 + r < M)
                v = *(const float4*)(Xg + (size_t)(row0 + r) * K + k0 + c * 4);
            __hip_bfloat16 o[4] = {__float2bfloat16(v.x), __float2bfloat16(v.y),
                                   __float2bfloat16(v.z), __float2bfloat16(v.w)};
            *(short4*)(As + r * LDK + c * 4) = *(short4*)o;
        }
        #pragma unroll
        for (int idx = t; idx < BN * 8; idx += 256) {
            int r = idx >> 3, c = idx & 7;
            uint4 v = *(const uint4*)(Wt + (size_t)r * K + k0 + c * 8);
            *(uint4*)(Bs + r * LDK + c * 8) = v;
        }
        __syncthreads();
        #pragma unroll
        for (int ks = 0; ks < 2; ++ks) {
            bf16x8 af[2], bfv[4];
            #pragma unroll
            for (int mt = 0; mt < 2; ++mt)
                af[mt] = *(const bf16x8*)(As + (m0 + mt * 16 + l15) * LDK + ks * 32 + quad * 8);
            #pragma unroll
            for (int nt = 0; nt < 4; ++nt)
                bfv[nt] = *(const bf16x8*)(Bs + (n0 + nt * 16 + l15) * LDK + ks * 32 + quad * 8);
            #pragma unroll
            for (int mt = 0; mt < 2; ++mt)
                #pragma unroll
                for (int nt = 0; nt < 4; ++nt)
                    acc[mt][nt] = __builtin_amdgcn_mfma_f32_16x16x32_bf16(
                        af[mt], bfv[nt], acc[mt][nt], 0, 0, 0);
        }
        __syncthreads();
    }
    #pragma unroll
    for (int mt = 0; mt < 2; ++mt) {
        #pragma unroll
        for (int reg = 0; reg < 4; ++reg) {
            int row = row0 + m0 + mt * 16 + quad * 4 + reg;
            if (row < M) {
                #pragma unroll
                for (int nt = 0; nt < 4; ++nt)
                    Ob[(size_t)row * BN + n0 + nt * 16 + l15] =
                        __float2bfloat16(acc[mt][nt][reg]);
            }
        }
    }
}

// ---------------------------------------------------------------------------
// Fused PN+GEMM: prologue reduces NSLICE stat slices -> mu/scale; A-staging
// applies relu((Bm-mu)*s) [+ Xb residual], optionally writes Xb. Block 0 zeros
// stats_out slices (ping-pong) for the next SpMM.
// ---------------------------------------------------------------------------
template<int BM, int BN, bool ADD_RESID, bool WRITE_X>
__global__ __launch_bounds__(256) void mfma_gemm_pn(const __hip_bfloat16* __restrict__ Bm,
                                                    __hip_bfloat16* __restrict__ Xb,
                                                    const float* __restrict__ stats_in,
                                                    float* __restrict__ stats_out,
                                                    const __hip_bfloat16* __restrict__ Wt,
                                                    __hip_bfloat16* __restrict__ Ob, int M) {
    constexpr int K = 128, BK = 64, LDK = 72;
    constexpr int WN = BN / 64;
    __shared__ short As[BM * LDK];
    __shared__ short Bs[BN * LDK];
    __shared__ float smu[128];
    __shared__ float sred[128];
    __shared__ float ssq16[NSLICE];
    __shared__ float sscale;
    int t = threadIdx.x;
    if (stats_out && blockIdx.x == 0)
        for (int z = t; z < NSLICE * SLICE_W; z += 256) stats_out[z] = 0.f;
    if (t < NSLICE) ssq16[t] = stats_in[t * SLICE_W + 128];
    if (t < 128) {
        float cs = 0.f;
        #pragma unroll
        for (int s = 0; s < NSLICE; ++s) cs += stats_in[s * SLICE_W + t];
        float mu = cs * (1.0f / N_NODES);
        smu[t] = mu;
        sred[t] = mu * mu;
    }
    __syncthreads();
    for (int off = 64; off > 0; off >>= 1) {
        if (t < off) sred[t] += sred[t + off];
        __syncthreads();
    }
    if (t == 0) {
        float sq = 0.f;
        #pragma unroll
        for (int s = 0; s < NSLICE; ++s) sq += ssq16[s];
        float ms = sq * (1.0f / N_NODES) - sred[0];
        sscale = 1.0f / sqrtf(1e-6f + ms);   // PN_SCALE = 1
    }
    __syncthreads();
    float sc = sscale;

    int lane = t & 63;
    int w = t >> 6;
    int wm = w / WN, wn = w % WN;
    int row0 = blockIdx.x * BM;
    int m0 = wm * 32, n0 = wn * 64;
    int l15 = lane & 15, quad = lane >> 4;

    f32x4 acc[2][4] = {};

    for (int k0 = 0; k0 < K; k0 += BK) {
        // A stage with fused PairNorm + ReLU + residual
        #pragma unroll
        for (int idx = t; idx < BM * 8; idx += 256) {
            int r = idx >> 3, c = idx & 7;
            int gr = row0 + r;
            int k = k0 + c * 8;
            uint4 bm = make_uint4(0u, 0u, 0u, 0u);
            uint4 xo = make_uint4(0u, 0u, 0u, 0u);
            bool ok = gr < M;
            if (ok) bm = *(const uint4*)(Bm + (size_t)gr * 128 + k);
            if (ADD_RESID && ok) xo = *(const uint4*)(Xb + (size_t)gr * 128 + k);
            unsigned short* bu = (unsigned short*)&bm;
            unsigned short* xu = (unsigned short*)&xo;
            __hip_bfloat16 o[8];
            #pragma unroll
            for (int j = 0; j < 8; ++j) {
                float v = fmaxf((bf2f(bu[j]) - smu[k + j]) * sc, 0.f);
                if (ADD_RESID) v += bf2f(xu[j]);
                o[j] = __float2bfloat16(v);
            }
            *(uint4*)(As + r * LDK + c * 8) = *(uint4*)o;
            if (WRITE_X && ok) *(uint4*)(Xb + (size_t)gr * 128 + k) = *(uint4*)o;
        }
        #pragma unroll
        for (int idx = t; idx < BN * 8; idx += 256) {
            int r = idx >> 3, c = idx & 7;
            uint4 v = *(const uint4*)(Wt + (size_t)r * K + k0 + c * 8);
            *(uint4*)(Bs + r * LDK + c * 8) = v;
        }
        __syncthreads();
        #pragma unroll
        for (int ks = 0; ks < 2; ++ks) {
            bf16x8 af[2], bfv[4];
            #pragma unroll
            for (int mt = 0; mt < 2; ++mt)
                af[mt] = *(const bf16x8*)(As + (m0 + mt * 16 + l15) * LDK + ks * 32 + quad * 8);
            #pragma unroll
            for (int nt = 0; nt < 4; ++nt)
                bfv[nt] = *(const bf16x8*)(Bs + (n0 + nt * 16 + l15) * LDK + ks * 32 + quad * 8);
            #pragma unroll
            for (int mt = 0; mt < 2; ++mt)
                #pragma unroll
                for (int nt = 0; nt < 4; ++nt)
                    acc[mt][nt] = __builtin_amdgcn_mfma_f32_16x16x32_bf16(
                        af[mt], bfv[nt], acc[mt][nt], 0, 0, 0);
        }
        __syncthreads();
    }
    #pragma unroll
    for (int mt = 0; mt < 2; ++mt) {
        #pragma unroll
        for (int reg = 0; reg < 4; ++reg) {
            int row = row0 + m0 + mt * 16 + quad * 4 + reg;
            if (row < M) {
                #pragma unroll
                for (int nt = 0; nt < 4; ++nt)
                    Ob[(size_t)row * BN + n0 + nt * 16 + l15] =
                        __float2bfloat16(acc[mt][nt][reg]);
            }
        }
    }
}

// ---------------------------------------------------------------------------
// CSR SpMM, 128 feats (R8 body: one wave per row; WAVE-UNIFORM cv loads ->
// s_loads, half-wave selects via cndmask — R9's h-in-address broke this).
// Fused PN stats epilogue: block LDS reduce -> 129 atomics into 1 of 16 slices.
// ---------------------------------------------------------------------------
__global__ __launch_bounds__(256) void spmm_bf16_kernel(const __hip_bfloat16* __restrict__ H,
                                                        const int* __restrict__ bptr,
                                                        const int2* __restrict__ cv,
                                                        const float* __restrict__ bias,
                                                        __hip_bfloat16* __restrict__ Bm,
                                                        float* __restrict__ stats,
                                                        int nrows) {
    __shared__ float sm[129];
    int t = threadIdx.x;
    if (t < 129) sm[t] = 0.f;
    __syncthreads();
    int wid = (int)((blockIdx.x * blockDim.x + t) >> 6);
    wid = __builtin_amdgcn_readfirstlane(wid);
    int lane = t & 63;
    int h = lane >> 5;
    int sub = lane & 31;                   // feats [4sub .. 4sub+3]
    if (wid < nrows) {
        int s = bptr[wid * NCB];
        int e = bptr[wid * NCB + NCB];
        const ushort4* H4 = (const ushort4*)H; // row stride = 32 ushort4
        f32x4 acc = {0.f, 0.f, 0.f, 0.f};
        int i = s;
        for (; i + 7 < e; i += 8) {        // 8 edges/iter: half h takes i+4h..i+4h+3
            int2 c0 = cv[i],     c1 = cv[i + 1], c2 = cv[i + 2], c3 = cv[i + 3];
            int2 c4 = cv[i + 4], c5 = cv[i + 5], c6 = cv[i + 6], c7 = cv[i + 7];
            int   ka = h ? c4.x : c0.x;  float va = __int_as_float(h ? c4.y : c0.y);
            int   kb = h ? c5.x : c1.x;  float vb = __int_as_float(h ? c5.y : c1.y);
            int   kc = h ? c6.x : c2.x;  float vc = __int_as_float(h ? c6.y : c2.y);
            int   kd = h ? c7.x : c3.x;  float vd = __int_as_float(h ? c7.y : c3.y);
            ushort4 ga = H4[(size_t)ka * 32 + sub];
            ushort4 gb = H4[(size_t)kb * 32 + sub];
            ushort4 gc = H4[(size_t)kc * 32 + sub];
            ushort4 gd = H4[(size_t)kd * 32 + sub];
            acc[0] = fmaf(va, bf2f(ga.x), acc[0]); acc[1] = fmaf(va, bf2f(ga.y), acc[1]);
            acc[2] = fmaf(va, bf2f(ga.z), acc[2]); acc[3] = fmaf(va, bf2f(ga.w), acc[3]);
            acc[0] = fmaf(vb, bf2f(gb.x), acc[0]); acc[1] = fmaf(vb, bf2f(gb.y), acc[1]);
            acc[2] = fmaf(vb, bf2f(gb.z), acc[2]); acc[3] = fmaf(vb, bf2f(gb.w), acc[3]);
            acc[0] = fmaf(vc, bf2f(gc.x), acc[0]); acc[1] = fmaf(vc, bf2f(gc.y), acc[1]);
            acc[2] = fmaf(vc, bf2f(gc.z), acc[2]); acc[3] = fmaf(vc, bf2f(gc.w), acc[3]);
            acc[0] = fmaf(vd, bf2f(gd.x), acc[0]); acc[1] = fmaf(vd, bf2f(gd.y), acc[1]);
            acc[2] = fmaf(vd, bf2f(gd.z), acc[2]); acc[3] = fmaf(vd, bf2f(gd.w), acc[3]);
        }
        for (; i + 3 < e; i += 4) {        // 4 edges: half h takes i+2h, i+2h+1
            int2 c0 = cv[i], c1 = cv[i + 1], c2 = cv[i + 2], c3 = cv[i + 3];
            int   ka = h ? c2.x : c0.x;  float va = __int_as_float(h ? c2.y : c0.y);
            int   kb = h ? c3.x : c1.x;  float vb = __int_as_float(h ? c3.y : c1.y);
            ushort4 ga = H4[(size_t)ka * 32 + sub];
            ushort4 gb = H4[(size_t)kb * 32 + sub];
            acc[0] = fmaf(va, bf2f(ga.x), acc[0]); acc[1] = fmaf(va, bf2f(ga.y), acc[1]);
            acc[2] = fmaf(va, bf2f(ga.z), acc[2]); acc[3] = fmaf(va, bf2f(ga.w), acc[3]);
            acc[0] = fmaf(vb, bf2f(gb.x), acc[0]); acc[1] = fmaf(vb, bf2f(gb.y), acc[1]);
            acc[2] = fmaf(vb, bf2f(gb.z), acc[2]); acc[3] = fmaf(vb, bf2f(gb.w), acc[3]);
        }
        for (; i < e; ++i) {               // tail: half0 only
            int2 c = cv[i];
            if (h == 0) {
                float v = __int_as_float(c.y);
                ushort4 g = H4[(size_t)c.x * 32 + sub];
                acc[0] = fmaf(v, bf2f(g.x), acc[0]); acc[1] = fmaf(v, bf2f(g.y), acc[1]);
                acc[2] = fmaf(v, bf2f(g.z), acc[2]); acc[3] = fmaf(v, bf2f(g.w), acc[3]);
            }
        }
        #pragma unroll
        for (int c = 0; c < 4; ++c) acc[c] += __shfl_xor(acc[c], 32);
        if (h == 0) {
            float4 b4 = *(const float4*)(bias + 4 * sub);
            float v0 = acc[0] + b4.x, v1 = acc[1] + b4.y;
            float v2 = acc[2] + b4.z, v3 = acc[3] + b4.w;
            __hip_bfloat16 o[4] = {__float2bfloat16(v0), __float2bfloat16(v1),
                                   __float2bfloat16(v2), __float2bfloat16(v3)};
            *(ushort4*)(Bm + (size_t)wid * 128 + 4 * sub) = *(ushort4*)o;
            // PN stats: lane owns cols 4sub..4sub+3 exclusively within its wave
            atomicAdd(&sm[4 * sub + 0], v0);
            atomicAdd(&sm[4 * sub + 1], v1);
            atomicAdd(&sm[4 * sub + 2], v2);
            atomicAdd(&sm[4 * sub + 3], v3);
            float sq = v0 * v0 + v1 * v1 + v2 * v2 + v3 * v3;
            #pragma unroll
            for (int off = 16; off > 0; off >>= 1) sq += __shfl_down(sq, off, 32);
            if (sub == 0) atomicAdd(&sm[128], sq);
        }
    }
    __syncthreads();
    if (t < 129)
        atomicAdd(&stats[(blockIdx.x & (NSLICE - 1)) * SLICE_W + t], sm[t]);
}

// ---------------------------------------------------------------------------
// Final SpMM, 64-wide G (cols 40..63 zero) — R8 body (wave-uniform cv loads)
// ---------------------------------------------------------------------------
__global__ __launch_bounds__(256) void spmm_out_kernel(const __hip_bfloat16* __restrict__ G,
                                                       const int* __restrict__ bptr,
                                                       const int2* __restrict__ cv,
                                                       const float* __restrict__ bias,
                                                       float* __restrict__ out, int nrows) {
    int wid = (int)((blockIdx.x * blockDim.x + threadIdx.x) >> 6);
    wid = __builtin_amdgcn_readfirstlane(wid);
    int lane = threadIdx.x & 63;
    int h = lane >> 5;
    int sub = lane & 31;                    // feats {2sub, 2sub+1}
    if (wid >= nrows) return;
    int s = bptr[wid * NCB];
    int e = bptr[wid * NCB + NCB];
    const __hip_bfloat162* G2 = (const __hip_bfloat162*)G;   // row stride 32
    float a0 = 0.f, a1 = 0.f;
    int i = s;
    for (; i + 7 < e; i += 8) {
        int2 c0 = cv[i],     c1 = cv[i + 1], c2 = cv[i + 2], c3 = cv[i + 3];
        int2 c4 = cv[i + 4], c5 = cv[i + 5], c6 = cv[i + 6], c7 = cv[i + 7];
        int   ka = h ? c4.x : c0.x;  float va = __int_as_float(h ? c4.y : c0.y);
        int   kb = h ? c5.x : c1.x;  float vb = __int_as_float(h ? c5.y : c1.y);
        int   kc = h ? c6.x : c2.x;  float vc = __int_as_float(h ? c6.y : c2.y);
        int   kd = h ? c7.x : c3.x;  float vd = __int_as_float(h ? c7.y : c3.y);
        __hip_bfloat162 ga = G2[(size_t)ka * 32 + sub];
        __hip_bfloat162 gb = G2[(size_t)kb * 32 + sub];
        __hip_bfloat162 gc = G2[(size_t)kc * 32 + sub];
        __hip_bfloat162 gd = G2[(size_t)kd * 32 + sub];
        a0 = fmaf(va, __bfloat162float(ga.x), a0); a1 = fmaf(va, __bfloat162float(ga.y), a1);
        a0 = fmaf(vb, __bfloat162float(gb.x), a0); a1 = fmaf(vb, __bfloat162float(gb.y), a1);
        a0 = fmaf(vc, __bfloat162float(gc.x), a0); a1 = fmaf(vc, __bfloat162float(gc.y), a1);
        a0 = fmaf(vd, __bfloat162float(gd.x), a0); a1 = fmaf(vd, __bfloat162float(gd.y), a1);
    }
    for (; i + 3 < e; i += 4) {
        int2 c0 = cv[i], c1 = cv[i + 1], c2 = cv[i + 2], c3 = cv[i + 3];
        int   ka = h ? c2.x : c0.x;  float va = __int_as_float(h ? c2.y : c0.y);
        int   kb = h ? c3.x : c1.x;  float vb = __int_as_float(h ? c3.y : c1.y);
        __hip_bfloat162 ga = G2[(size_t)ka * 32 + sub];
        __hip_bfloat162 gb = G2[(size_t)kb * 32 + sub];
        a0 = fmaf(va, __bfloat162float(ga.x), a0); a1 = fmaf(va, __bfloat162float(ga.y), a1);
        a0 = fmaf(vb, __bfloat162float(gb.x), a0); a1 = fmaf(vb, __bfloat162float(gb.y), a1);
    }
    for (; i < e; ++i) {
        int2 c = cv[i];
        if (h == 0) {
            float v = __int_as_float(c.y);
            __hip_bfloat162 g = G2[(size_t)c.x * 32 + sub];
            a0 = fmaf(v, __bfloat162float(g.x), a0);
            a1 = fmaf(v, __bfloat162float(g.y), a1);
        }
    }
    a0 += __shfl_xor(a0, 32);
    a1 += __shfl_xor(a1, 32);
    if (h == 0 && sub < NCLASS / 2) {
        float2 b2 = *(const float2*)(bias + 2 * sub);
        float2 o = make_float2(a0 + b2.x, a1 + b2.y);
        *(float2*)(out + (size_t)wid * NCLASS + 2 * sub) = o;
    }
}

// ---------------------------------------------------------------------------
extern "C" void kernel_launch(void* const* d_in, const int* in_sizes, int n_in,
                              void* d_out, int out_size, void* d_ws, size_t ws_size,
                              hipStream_t stream) {
    const float* x        = (const float*)d_in[0];
    const int*   edge_row = (const int*)  d_in[1];
    const int*   edge_col = (const int*)  d_in[2];
    const float* edge_val = (const float*)d_in[3];
    const float* W0 = (const float*)d_in[4];
    const float* b0 = (const float*)d_in[5];
    const float* W1 = (const float*)d_in[6];
    const float* b1 = (const float*)d_in[7];
    const float* W2 = (const float*)d_in[8];
    const float* b2 = (const float*)d_in[9];
    const float* W_out = (const float*)d_in[10];
    const float* b_out = (const float*)d_in[11];
    float* out = (float*)d_out;

    const size_t NH = (size_t)N_NODES * NHID;   // 6,400,000

    char* p = (char*)d_ws;
    __hip_bfloat16* Xb   = (__hip_bfloat16*)p;  p += NH * 2;
    __hip_bfloat16* A_bf = (__hip_bfloat16*)p;  p += NH * 2;
    __hip_bfloat16* Bm   = (__hip_bfloat16*)p;  p += NH * 2;
    __hip_bfloat16* Wt0 = (__hip_bfloat16*)p;   p += (size_t)128 * 512 * 2;
    __hip_bfloat16* Wt1 = (__hip_bfloat16*)p;   p += (size_t)128 * 128 * 2;
    __hip_bfloat16* Wt2 = (__hip_bfloat16*)p;   p += (size_t)128 * 128 * 2;
    __hip_bfloat16* Wot = (__hip_bfloat16*)p;   p += (size_t)64 * 128 * 2;
    float* statsA   = (float*)p;                p += (size_t)NSLICE * SLICE_W * 4;
    float* statsB   = (float*)p;                p += (size_t)NSLICE * SLICE_W * 4;
    int* cnt      = (int*)p;                    p += (size_t)NCNT * 4;
    int* bptr     = (int*)p;                    p += (size_t)(NCNT + 1) * 4 + 4; // int2 align
    int* cursor   = (int*)p;                    p += (size_t)NCNT * 4;
    int* bsum     = (int*)p;                    p += (size_t)SCAN_BLOCKS * 4 + 4;
    int2* csr_cv  = (int2*)p;                   p += (size_t)N_EDGES * 8;

    const int EB = (N_EDGES + 255) / 256;         // 3125 blocks per pass
    const int SPMM_GRID = (N_NODES + 3) / 4;      // 12500 (4 waves/block)
    const int GEMM0_BLOCKS = (N_NODES + 63) / 64; // 782

    // --- CSR build + weight conversion (merged/overlapped) ---
    hipMemsetAsync(cnt, 0, NCNT * sizeof(int), stream);
    wt_hist_kernel<<<WT_BLOCKS + EB, 256, 0, stream>>>(
        W0, W1, W2, W_out, Wt0, Wt1, Wt2, Wot, edge_row, edge_col, cnt, N_EDGES);
    scan_p1_kernel<<<SCAN_BLOCKS, 1024, 0, stream>>>(cnt, bsum, NCNT);
    scan_p2_kernel<<<1, 512, 0, stream>>>(bsum, SCAN_BLOCKS);
    scan_p3_kernel<<<SCAN_BLOCKS, 1024, 0, stream>>>(cnt, bsum, bptr, cursor, NCNT);

    // --- layer 0 GEMM (zeros statsA) + scatter, one launch ---
    gemm0_scatter_kernel<64, 128, 512><<<GEMM0_BLOCKS + EB * NPASS, 256, 0, stream>>>(
        x, Wt0, A_bf, statsA, N_NODES,
        edge_row, edge_col, edge_val, cursor, csr_cv, N_EDGES, EB, GEMM0_BLOCKS);
    spmm_bf16_kernel<<<SPMM_GRID, 256, 0, stream>>>(A_bf, bptr, csr_cv, b0, Bm,
                                                    statsA, N_NODES);

    // --- layer 1: PN(statsA)+GEMM (writes Xb=x1, zeros statsB) -> SpMM(statsB)
    mfma_gemm_pn<64, 128, false, true><<<GEMM0_BLOCKS, 256, 0, stream>>>(
        Bm, Xb, statsA, statsB, Wt1, A_bf, N_NODES);
    spmm_bf16_kernel<<<SPMM_GRID, 256, 0, stream>>>(A_bf, bptr, csr_cv, b1, Bm,
                                                    statsB, N_NODES);

    // --- layer 2: PN(statsB)+resid+GEMM (Xb=x2, zeros statsA) -> SpMM(statsA)
    mfma_gemm_pn<64, 128, true, true><<<GEMM0_BLOCKS, 256, 0, stream>>>(
        Bm, Xb, statsB, statsA, Wt2, A_bf, N_NODES);
    spmm_bf16_kernel<<<SPMM_GRID, 256, 0, stream>>>(A_bf, bptr, csr_cv, b2, Bm,
                                                    statsA, N_NODES);

    // --- head: PN(statsA)+resid(x2), x3 never materialized; Gp = x3 @ Wot^T ---
    mfma_gemm_pn<128, 64, true, false><<<(N_NODES + 127) / 128, 256, 0, stream>>>(
        Bm, Xb, statsA, nullptr, Wot, A_bf, N_NODES);
    spmm_out_kernel<<<(N_NODES + 3) / 4, 256, 0, stream>>>(A_bf, bptr, csr_cv, b_out,
                                                           out, N_NODES);
}